// Round 10
// baseline (265.921 us; speedup 1.0000x reference)
//
#include <hip/hip_runtime.h>
#include <hip/hip_bf16.h>
#include <hip/hip_cooperative_groups.h>
#include <cstdint>

namespace cg = cooperative_groups;

// out[M,N] = x[M,K] @ weight[N,K]^T, fp32 device buffers.
// Cooperative kernel, grid 256 x 512thr, 1 block/CU (128 KB LDS):
//  phase 1: cvt fp32->bf16 into d_ws, [koct][row][8] chunk layout
//  grid.sync()
//  phase 2: 256x256 GEMM, BK=64, 8 waves (2x4), 32x32x16 MFMA.
//  Barrier-light K-tile: stage ALL of tile t+1 at top (vmcnt(8) retires
//  compute set exactly - never 0), publish barrier, then 4 ks-groups of
//  {6 ds_read_b128 + 8 MFMA} with NO internal barriers (compiler
//  free-schedules reads under MFMA), lgkmcnt(0)+barrier at tile end.

typedef __bf16 bf16x8 __attribute__((ext_vector_type(8)));
typedef float f32x16 __attribute__((ext_vector_type(16)));
typedef float f32x4 __attribute__((ext_vector_type(4)));
typedef unsigned short u16x8 __attribute__((ext_vector_type(8)));

#define GAS __attribute__((address_space(1)))
#define LAS __attribute__((address_space(3)))
#define ASYNC16(gsrc, ldst)                                                  \
    __builtin_amdgcn_global_load_lds((GAS uint32_t*)(const void*)(gsrc),     \
                                     (LAS uint32_t*)(ldst), 16, 0, 0)

__device__ inline unsigned short f2bf(float f) {
    __hip_bfloat16 h = __float2bfloat16(f);  // RNE
    return *reinterpret_cast<unsigned short*>(&h);
}

__global__ __launch_bounds__(512, 1) void coop_cvt_gemm5(
    const float* __restrict__ A32,       // x      [M,K]
    const float* __restrict__ B32,       // weight [N,K]
    unsigned short* __restrict__ ws,     // bf16 tiled [szX | szW]
    float* __restrict__ C,               // out    [M,N]
    int M, int N, int K)
{
    const int NT  = K >> 6;              // 64 K-tiles
    const int szX = M * K;
    const int szW = N * K;

    // ================= phase 1: cvt fp32 -> tiled bf16 ws =================
    // chunk (16384 shorts) per (tile,kt); within: off = koct*2048 + row*8 + e
    // where k = kt*64 + koct*8.  (same layout as R7/R8, validated)
    {
        const int nA8  = szX >> 3;
        const int tot8 = (szX + szW) >> 3;
        const int S = gridDim.x * blockDim.x;
        for (int c = blockIdx.x * blockDim.x + threadIdx.x; c < tot8; c += S) {
            unsigned short* dst = ws + ((size_t)c << 3);
            int cl; const float* base;
            if (c < nA8) { cl = c;       base = A32; }
            else         { cl = c - nA8; base = B32; }
            const int cid  = cl >> 11;          // (tile,kt) chunk id
            const int c_in = cl & 2047;         // 8-short group within chunk
            const int koct = c_in >> 8;         // 0..7
            const int row  = c_in & 255;
            const float* src = base + (size_t)((cid >> 6) * 256 + row) * K
                                    + (cid & 63) * 64 + koct * 8;
            float4 v0 = *reinterpret_cast<const float4*>(src);
            float4 v1 = *reinterpret_cast<const float4*>(src + 4);
            u16x8 o;
            o[0] = f2bf(v0.x); o[1] = f2bf(v0.y); o[2] = f2bf(v0.z); o[3] = f2bf(v0.w);
            o[4] = f2bf(v1.x); o[5] = f2bf(v1.y); o[6] = f2bf(v1.z); o[7] = f2bf(v1.w);
            *reinterpret_cast<u16x8*>(dst) = o;
        }
    }

    cg::this_grid().sync();
    asm volatile("s_waitcnt vmcnt(0)" ::: "memory");   // clean vmcnt ledger

    // ================= phase 2: GEMM (32x32x16, barrier-light) =================
    __shared__ unsigned short lds[2][2][16384];        // [set][A|B] = 128 KB

    const int nbm = M >> 8;              // 8
    const int nbn = N >> 8;              // 32
    const int bid = blockIdx.x;
    const int swzid = (bid & 7) * ((nbm * nbn) >> 3) + (bid >> 3);
    const int bm = swzid % nbm;          // fast: stream A panels
    const int bn = swzid / nbm;          // slow: B panel L2-resident

    const int tid  = threadIdx.x;
    const int wv   = tid >> 6;
    const int lane = tid & 63;
    const int wr   = wv >> 2;            // 0..1  (wave owns 128x64 of C)
    const int wc   = wv & 3;             // 0..3

    // staging: wave wv copies shorts [wv*2048, wv*2048+2048) of each 32KB chunk
    const unsigned short* wsA = ws + (size_t)(bm * NT) * 16384 + wv * 2048 + lane * 8;
    const unsigned short* wsB = ws + (size_t)szX + (size_t)(bn * NT) * 16384 + wv * 2048 + lane * 8;

    // fragment bases (shorts): A row = wr*128 + mb*32 + lo, k-oct = ks*2 + hi
    const int lo = lane & 31, hi = lane >> 5;
    const int aBase = hi * 2048 + (wr * 128 + lo) * 8;   // + ks*4096 + mb*256
    const int bBase = hi * 2048 + (wc * 64 + lo) * 8;    // + ks*4096 + nb*256

    f32x16 acc00 = {}, acc01 = {}, acc10 = {}, acc11 = {};
    f32x16 acc20 = {}, acc21 = {}, acc30 = {}, acc31 = {};

#define STAGE_ALL(tt, ss) do {                                                \
        const unsigned short* sA_ = wsA + (size_t)(tt) * 16384;               \
        const unsigned short* sB_ = wsB + (size_t)(tt) * 16384;               \
        ASYNC16(sA_,        &lds[ss][0][wv * 2048]);                          \
        ASYNC16(sA_ + 512,  &lds[ss][0][wv * 2048 + 512]);                    \
        ASYNC16(sA_ + 1024, &lds[ss][0][wv * 2048 + 1024]);                   \
        ASYNC16(sA_ + 1536, &lds[ss][0][wv * 2048 + 1536]);                   \
        ASYNC16(sB_,        &lds[ss][1][wv * 2048]);                          \
        ASYNC16(sB_ + 512,  &lds[ss][1][wv * 2048 + 512]);                    \
        ASYNC16(sB_ + 1024, &lds[ss][1][wv * 2048 + 1024]);                   \
        ASYNC16(sB_ + 1536, &lds[ss][1][wv * 2048 + 1536]);                   \
    } while (0)
#define READK(ss, ks, A0_, A1_, A2_, A3_, B0_, B1_) do {                      \
        A0_ = *(const bf16x8*)&lds[ss][0][aBase + (ks) * 4096 + 0 * 256];     \
        A1_ = *(const bf16x8*)&lds[ss][0][aBase + (ks) * 4096 + 1 * 256];     \
        A2_ = *(const bf16x8*)&lds[ss][0][aBase + (ks) * 4096 + 2 * 256];     \
        A3_ = *(const bf16x8*)&lds[ss][0][aBase + (ks) * 4096 + 3 * 256];     \
        B0_ = *(const bf16x8*)&lds[ss][1][bBase + (ks) * 4096 + 0 * 256];     \
        B1_ = *(const bf16x8*)&lds[ss][1][bBase + (ks) * 4096 + 1 * 256];     \
    } while (0)
#define MFMA8(A0_, A1_, A2_, A3_, B0_, B1_) do {                              \
        __builtin_amdgcn_s_setprio(1);                                        \
        acc00 = __builtin_amdgcn_mfma_f32_32x32x16_bf16(A0_, B0_, acc00, 0, 0, 0); \
        acc01 = __builtin_amdgcn_mfma_f32_32x32x16_bf16(A0_, B1_, acc01, 0, 0, 0); \
        acc10 = __builtin_amdgcn_mfma_f32_32x32x16_bf16(A1_, B0_, acc10, 0, 0, 0); \
        acc11 = __builtin_amdgcn_mfma_f32_32x32x16_bf16(A1_, B1_, acc11, 0, 0, 0); \
        acc20 = __builtin_amdgcn_mfma_f32_32x32x16_bf16(A2_, B0_, acc20, 0, 0, 0); \
        acc21 = __builtin_amdgcn_mfma_f32_32x32x16_bf16(A2_, B1_, acc21, 0, 0, 0); \
        acc30 = __builtin_amdgcn_mfma_f32_32x32x16_bf16(A3_, B0_, acc30, 0, 0, 0); \
        acc31 = __builtin_amdgcn_mfma_f32_32x32x16_bf16(A3_, B1_, acc31, 0, 0, 0); \
        __builtin_amdgcn_s_setprio(0);                                        \
    } while (0)
// One K-tile: stage ALL of tile tn -> ss^1 (8 loads), vmcnt(8) retires the
// 8 loads of set ss (FIFO: 8 old + 8 new = 16 -> wait 8), publish barrier,
// then 4 ks-groups with no internal barriers; lgkmcnt(0)+barrier at end
// (all reads of ss complete before anyone stages into ss next K-tile).
#define KTILE(ss, tn) do {                                                    \
        STAGE_ALL(tn, (ss) ^ 1);                                              \
        asm volatile("s_waitcnt vmcnt(8)" ::: "memory");                      \
        __builtin_amdgcn_s_barrier();                                         \
        __builtin_amdgcn_sched_barrier(0);                                    \
        bf16x8 a0, a1, a2, a3, b0, b1, c0, c1, c2, c3, d0, d1;                \
        READK(ss, 0, a0, a1, a2, a3, b0, b1);                                 \
        READK(ss, 1, c0, c1, c2, c3, d0, d1);                                 \
        MFMA8(a0, a1, a2, a3, b0, b1);                                        \
        READK(ss, 2, a0, a1, a2, a3, b0, b1);                                 \
        MFMA8(c0, c1, c2, c3, d0, d1);                                        \
        READK(ss, 3, c0, c1, c2, c3, d0, d1);                                 \
        MFMA8(a0, a1, a2, a3, b0, b1);                                        \
        MFMA8(c0, c1, c2, c3, d0, d1);                                        \
        asm volatile("s_waitcnt lgkmcnt(0)" ::: "memory");                    \
        __builtin_amdgcn_s_barrier();                                         \
        __builtin_amdgcn_sched_barrier(0);                                    \
    } while (0)

    // prologue: tile 0 -> set 0 (outstanding = 8, matches steady state)
    STAGE_ALL(0, 0);

    for (int t = 0; t < NT; t += 2) {
        const int tn1 = t + 1;                          // <= NT-1
        KTILE(0, tn1);
        const int tn2 = (t + 2 < NT) ? t + 2 : NT - 1;  // tail: redundant restage
        KTILE(1, tn2);
    }

    // ---- epilogue: 32x32 C/D layout (m74/m101-verified):
    // col = lane&31 (+nb*32), row = (reg&3) + 8*(reg>>2) + 4*hi (+mb*32)
    {
        const int crowB = bm * 256 + wr * 128 + 4 * hi;
        const int ccolB = bn * 256 + wc * 64 + lo;
        const f32x16* accp[4][2] = {{&acc00, &acc01}, {&acc10, &acc11},
                                    {&acc20, &acc21}, {&acc30, &acc31}};
#pragma unroll
        for (int mb = 0; mb < 4; ++mb)
#pragma unroll
            for (int nb = 0; nb < 2; ++nb) {
                const f32x16 v = *accp[mb][nb];
#pragma unroll
                for (int reg = 0; reg < 16; ++reg) {
                    const int row = crowB + mb * 32 + (reg & 3) + 8 * (reg >> 2);
                    C[(size_t)row * N + (ccolB + nb * 32)] = v[reg];
                }
            }
    }

#undef STAGE_ALL
#undef READK
#undef MFMA8
#undef KTILE
}

// ---------------- fallback: Round-4 fused kernel (proven PASS) ----------------
__device__ inline int lds_off(int row, int slot) {
    return row * 32 + (((slot ^ ((row >> 1) & 3)) & 3) << 3);
}

__global__ __launch_bounds__(256) void gemm_bt_fused(
    const float* __restrict__ A, const float* __restrict__ B,
    float* __restrict__ C, int M, int N, int K)
{
    constexpr int BM = 128, BN = 128, BK = 32;
    __shared__ unsigned short sA[2][BM * BK];
    __shared__ unsigned short sB[2][BN * BK];

    const int nbm = M / BM, nbn = N / BN;
    const int nwg = nbm * nbn;
    const int bid = blockIdx.x;
    int swz = bid;
    if ((nwg & 7) == 0) { const int q = nwg >> 3; swz = (bid & 7) * q + (bid >> 3); }
    const int bm = swz % nbm, bn = swz / nbm;

    const int tid = threadIdx.x;
    const int srow = tid >> 1;
    const int scol = (tid & 1) * 16;
    const float* gA = A + (size_t)(bm * BM + srow) * K + scol;
    const float* gB = B + (size_t)(bn * BN + srow) * K + scol;
    const int s0  = (tid & 1) * 2;
    const int wo0 = lds_off(srow, s0);
    const int wo1 = lds_off(srow, s0 + 1);

    const int wave = tid >> 6, lane = tid & 63;
    const int wr = wave >> 1, wc = wave & 1;
    const int fr = lane & 15;
    const int slr = lane >> 4;
    int offA[4], offB[4];
#pragma unroll
    for (int i = 0; i < 4; ++i) {
        offA[i] = lds_off(wr * 64 + i * 16 + fr, slr);
        offB[i] = lds_off(wc * 64 + i * 16 + fr, slr);
    }

    f32x4 acc[4][4] = {};
    const int NT = K / BK;

    float4 va[4], vb[4];
#pragma unroll
    for (int p = 0; p < 4; ++p) {
        va[p] = *reinterpret_cast<const float4*>(gA + p * 4);
        vb[p] = *reinterpret_cast<const float4*>(gB + p * 4);
    }

    for (int t = 0; t < NT; ++t) {
        const int cur = t & 1;
        u16x8 pa0, pa1, pb0, pb1;
#pragma unroll
        for (int e = 0; e < 4; ++e) {
            pa0[e] = f2bf(va[0][e]);  pa0[4 + e] = f2bf(va[1][e]);
            pa1[e] = f2bf(va[2][e]);  pa1[4 + e] = f2bf(va[3][e]);
            pb0[e] = f2bf(vb[0][e]);  pb0[4 + e] = f2bf(vb[1][e]);
            pb1[e] = f2bf(vb[2][e]);  pb1[4 + e] = f2bf(vb[3][e]);
        }
        *reinterpret_cast<u16x8*>(&sA[cur][wo0]) = pa0;
        *reinterpret_cast<u16x8*>(&sA[cur][wo1]) = pa1;
        *reinterpret_cast<u16x8*>(&sB[cur][wo0]) = pb0;
        *reinterpret_cast<u16x8*>(&sB[cur][wo1]) = pb1;

        const int kn = (t + 1 < NT) ? (t + 1) * BK : t * BK;
#pragma unroll
        for (int p = 0; p < 4; ++p) {
            va[p] = *reinterpret_cast<const float4*>(gA + kn + p * 4);
            vb[p] = *reinterpret_cast<const float4*>(gB + kn + p * 4);
        }

        __syncthreads();

        bf16x8 a[4], b[4];
#pragma unroll
        for (int i = 0; i < 4; ++i) a[i] = *reinterpret_cast<const bf16x8*>(&sA[cur][offA[i]]);
#pragma unroll
        for (int j = 0; j < 4; ++j) b[j] = *reinterpret_cast<const bf16x8*>(&sB[cur][offB[j]]);
#pragma unroll
        for (int i = 0; i < 4; ++i)
#pragma unroll
            for (int j = 0; j < 4; ++j)
                acc[i][j] = __builtin_amdgcn_mfma_f32_16x16x32_bf16(a[i], b[j], acc[i][j], 0, 0, 0);
    }

    const int crow0 = bm * BM + wr * 64 + (lane >> 4) * 4;
    const int ccol0 = bn * BN + wc * 64 + fr;
#pragma unroll
    for (int i = 0; i < 4; ++i)
#pragma unroll
        for (int j = 0; j < 4; ++j)
#pragma unroll
            for (int r = 0; r < 4; ++r)
                C[(size_t)(crow0 + i * 16 + r) * N + (ccol0 + j * 16)] = acc[i][j][r];
}

extern "C" void kernel_launch(void* const* d_in, const int* in_sizes, int n_in,
                              void* d_out, int out_size, void* d_ws, size_t ws_size,
                              hipStream_t stream) {
    int K = 4096;
    int M = in_sizes[0] / K;   // 2048
    int N = in_sizes[1] / K;   // 8192

    const float* x = (const float*)d_in[0];
    const float* w = (const float*)d_in[1];
    float* out     = (float*)d_out;
    unsigned short* wsp = (unsigned short*)d_ws;

    const size_t need = ((size_t)in_sizes[0] + (size_t)in_sizes[1]) * 2;
    const int nwg2 = (M >> 8) * (N >> 8);   // 256

    bool geom_ok = (M % 256 == 0) && (N % 256 == 0) && (K % 128 == 0) &&
                   ((((M >> 8) * (N >> 8)) & 7) == 0);
    int maxB = 0;
    hipError_t oe = hipOccupancyMaxActiveBlocksPerMultiprocessor(&maxB, coop_cvt_gemm5, 512, 0);
    const bool coop_ok = geom_ok && (oe == hipSuccess) && (ws_size >= need) &&
                         ((long long)maxB * 256 >= (long long)nwg2);

    if (coop_ok) {
        void* args[] = {(void*)&x, (void*)&w, (void*)&wsp, (void*)&out,
                        (void*)&M, (void*)&N, (void*)&K};
        hipError_t le = hipLaunchCooperativeKernel(coop_cvt_gemm5, dim3(nwg2), dim3(512),
                                                   args, 0, stream);
        if (le == hipSuccess) return;
    }
    const int nwg = (M / 128) * (N / 128);
    gemm_bt_fused<<<dim3(nwg), dim3(256), 0, stream>>>(x, w, out, M, N, K);
}

// Round 11
// 265.617 us; speedup vs baseline: 1.0011x; 1.0011x over previous
//
#include <hip/hip_runtime.h>
#include <hip/hip_bf16.h>
#include <hip/hip_cooperative_groups.h>
#include <cstdint>

namespace cg = cooperative_groups;

// out[M,N] = x[M,K] @ weight[N,K]^T, fp32 device buffers.
// Cooperative kernel, grid 1024 x 256thr = 4 blocks/CU (32 KB LDS each):
//  phase 1: cvt fp32->bf16 into d_ws, chunked [koct][row][8] layout, x2 unroll
//  grid.sync()
//  phase 2: 128x128 GEMM, BK=32, 4 waves (64x64/wave), 32x32x16 MFMA,
//  double-buffered LDS, counted vmcnt(4), 2 barriers/K-tile. Co-residency
//  (4 blocks/CU) hides barrier stalls - the m97/m114 mechanism - instead of
//  1-block/CU hand scheduling (R7-R10 plateau ~810 TF).

typedef __bf16 bf16x8 __attribute__((ext_vector_type(8)));
typedef float f32x16 __attribute__((ext_vector_type(16)));
typedef float f32x4 __attribute__((ext_vector_type(4)));
typedef unsigned short u16x8 __attribute__((ext_vector_type(8)));

#define GAS __attribute__((address_space(1)))
#define LAS __attribute__((address_space(3)))
#define ASYNC16(gsrc, ldst)                                                  \
    __builtin_amdgcn_global_load_lds((GAS uint32_t*)(const void*)(gsrc),     \
                                     (LAS uint32_t*)(ldst), 16, 0, 0)

__device__ inline unsigned short f2bf(float f) {
    __hip_bfloat16 h = __float2bfloat16(f);  // RNE
    return *reinterpret_cast<unsigned short*>(&h);
}

// cvt source address for linear 8-group index cl within one matrix:
// chunk (4096 shorts) per (tile128, kt32); within: off = koct*1024 + row*8 + e,
// k = kt*32 + koct*8 + e.
__device__ inline const float* cvt_src(const float* base, int cl, int K) {
    const int cid  = cl >> 9;           // chunk id = tile*(K/32) + kt
    const int c_in = cl & 511;
    const int kt   = cid & ((K >> 5) - 1);
    const int tile = cid / (K >> 5);
    const int koct = c_in >> 7;
    const int row  = c_in & 127;
    return base + (size_t)(tile * 128 + row) * K + kt * 32 + koct * 8;
}

__global__ __launch_bounds__(256, 4) void coop_cvt_gemm6(
    const float* __restrict__ A32,       // x      [M,K]
    const float* __restrict__ B32,       // weight [N,K]
    unsigned short* __restrict__ ws,     // bf16 tiled [szX | szW]
    float* __restrict__ C,               // out    [M,N]
    int M, int N, int K)
{
    const int NT  = K >> 5;              // 128 K-tiles (BK=32)
    const int szX = M * K;
    const int szW = N * K;

    // ================= phase 1: cvt fp32 -> tiled bf16 ws (x2 unroll) =====
    {
        const int nA8  = szX >> 3;
        const int tot8 = (szX + szW) >> 3;
        const int S = gridDim.x * blockDim.x;
        int c = blockIdx.x * blockDim.x + threadIdx.x;
        for (; c + S < tot8; c += 2 * S) {
            const int c1 = c + S;
            const float* s0 = (c  < nA8) ? cvt_src(A32, c,        K)
                                         : cvt_src(B32, c  - nA8, K);
            const float* s1 = (c1 < nA8) ? cvt_src(A32, c1,       K)
                                         : cvt_src(B32, c1 - nA8, K);
            float4 v0a = *reinterpret_cast<const float4*>(s0);
            float4 v0b = *reinterpret_cast<const float4*>(s0 + 4);
            float4 v1a = *reinterpret_cast<const float4*>(s1);
            float4 v1b = *reinterpret_cast<const float4*>(s1 + 4);
            u16x8 o0, o1;
            o0[0] = f2bf(v0a.x); o0[1] = f2bf(v0a.y); o0[2] = f2bf(v0a.z); o0[3] = f2bf(v0a.w);
            o0[4] = f2bf(v0b.x); o0[5] = f2bf(v0b.y); o0[6] = f2bf(v0b.z); o0[7] = f2bf(v0b.w);
            o1[0] = f2bf(v1a.x); o1[1] = f2bf(v1a.y); o1[2] = f2bf(v1a.z); o1[3] = f2bf(v1a.w);
            o1[4] = f2bf(v1b.x); o1[5] = f2bf(v1b.y); o1[6] = f2bf(v1b.z); o1[7] = f2bf(v1b.w);
            *reinterpret_cast<u16x8*>(ws + ((size_t)c  << 3)) = o0;
            *reinterpret_cast<u16x8*>(ws + ((size_t)c1 << 3)) = o1;
        }
        for (; c < tot8; c += S) {
            const float* s0 = (c < nA8) ? cvt_src(A32, c, K) : cvt_src(B32, c - nA8, K);
            float4 va = *reinterpret_cast<const float4*>(s0);
            float4 vb = *reinterpret_cast<const float4*>(s0 + 4);
            u16x8 o;
            o[0] = f2bf(va.x); o[1] = f2bf(va.y); o[2] = f2bf(va.z); o[3] = f2bf(va.w);
            o[4] = f2bf(vb.x); o[5] = f2bf(vb.y); o[6] = f2bf(vb.z); o[7] = f2bf(vb.w);
            *reinterpret_cast<u16x8*>(ws + ((size_t)c << 3)) = o;
        }
    }

    cg::this_grid().sync();
    asm volatile("s_waitcnt vmcnt(0)" ::: "memory");   // clean vmcnt ledger

    // ================= phase 2: GEMM (128^2, BK=32, 4 blocks/CU) ==========
    __shared__ unsigned short lds[2][2][4096];         // [set][A|B] = 32 KB

    const int nbm = M >> 7;              // 16
    const int nbn = N >> 7;              // 64
    const int nwg = nbm * nbn;           // 1024
    const int bid = blockIdx.x;
    const int swzid = (bid & 7) * (nwg >> 3) + (bid >> 3);
    const int bm = swzid % nbm;          // fast: stream A panels
    const int bn = swzid / nbm;          // slow: B panel L2-resident per XCD

    const int tid  = threadIdx.x;
    const int wv   = tid >> 6;
    const int lane = tid & 63;
    const int wr   = wv >> 1;            // 0..1  (wave owns 64x64 of C)
    const int wc   = wv & 1;             // 0..1
    const int lo   = lane & 31, hi = lane >> 5;

    // staging: thread copies 2x16B of A-chunk and 2x16B of B-chunk
    const unsigned short* wsA = ws + (size_t)(bm * NT) * 4096 + wv * 512 + lane * 8;
    const unsigned short* wsB = ws + (size_t)szX + (size_t)(bn * NT) * 4096 + wv * 512 + lane * 8;

    // fragment offsets (shorts): koct = ks*2 + hi, row/col = w*64 + f*32 + lo
    int aOff[2][2], bOff[2][2];
#pragma unroll
    for (int ks = 0; ks < 2; ++ks)
#pragma unroll
        for (int f = 0; f < 2; ++f) {
            aOff[ks][f] = (ks * 2 + hi) * 1024 + (wr * 64 + f * 32 + lo) * 8;
            bOff[ks][f] = (ks * 2 + hi) * 1024 + (wc * 64 + f * 32 + lo) * 8;
        }

    f32x16 acc00 = {}, acc01 = {}, acc10 = {}, acc11 = {};

#define STAGE_ALL(tt, ss) do {                                                \
        const unsigned short* sA_ = wsA + (size_t)(tt) * 4096;                \
        const unsigned short* sB_ = wsB + (size_t)(tt) * 4096;                \
        ASYNC16(sA_,        &lds[ss][0][wv * 512]);                           \
        ASYNC16(sA_ + 2048, &lds[ss][0][wv * 512 + 2048]);                    \
        ASYNC16(sB_,        &lds[ss][1][wv * 512]);                           \
        ASYNC16(sB_ + 2048, &lds[ss][1][wv * 512 + 2048]);                    \
    } while (0)
// One K-tile: stage tile tn -> ss^1 (4 loads); vmcnt(4) retires set ss's 4
// (FIFO: 4 old + 4 new -> wait 4; never 0 in loop); publish barrier; 8 reads
// + 8 MFMA; lgkmcnt(0)+barrier protects ss before next staging.
#define KTILE(ss, tn) do {                                                    \
        STAGE_ALL(tn, (ss) ^ 1);                                              \
        asm volatile("s_waitcnt vmcnt(4)" ::: "memory");                      \
        __builtin_amdgcn_s_barrier();                                         \
        __builtin_amdgcn_sched_barrier(0);                                    \
        bf16x8 a00 = *(const bf16x8*)&lds[ss][0][aOff[0][0]];                 \
        bf16x8 a01 = *(const bf16x8*)&lds[ss][0][aOff[0][1]];                 \
        bf16x8 b00 = *(const bf16x8*)&lds[ss][1][bOff[0][0]];                 \
        bf16x8 b01 = *(const bf16x8*)&lds[ss][1][bOff[0][1]];                 \
        bf16x8 a10 = *(const bf16x8*)&lds[ss][0][aOff[1][0]];                 \
        bf16x8 a11 = *(const bf16x8*)&lds[ss][0][aOff[1][1]];                 \
        bf16x8 b10 = *(const bf16x8*)&lds[ss][1][bOff[1][0]];                 \
        bf16x8 b11 = *(const bf16x8*)&lds[ss][1][bOff[1][1]];                 \
        __builtin_amdgcn_s_setprio(1);                                        \
        acc00 = __builtin_amdgcn_mfma_f32_32x32x16_bf16(a00, b00, acc00, 0, 0, 0); \
        acc01 = __builtin_amdgcn_mfma_f32_32x32x16_bf16(a00, b01, acc01, 0, 0, 0); \
        acc10 = __builtin_amdgcn_mfma_f32_32x32x16_bf16(a01, b00, acc10, 0, 0, 0); \
        acc11 = __builtin_amdgcn_mfma_f32_32x32x16_bf16(a01, b01, acc11, 0, 0, 0); \
        acc00 = __builtin_amdgcn_mfma_f32_32x32x16_bf16(a10, b10, acc00, 0, 0, 0); \
        acc01 = __builtin_amdgcn_mfma_f32_32x32x16_bf16(a10, b11, acc01, 0, 0, 0); \
        acc10 = __builtin_amdgcn_mfma_f32_32x32x16_bf16(a11, b10, acc10, 0, 0, 0); \
        acc11 = __builtin_amdgcn_mfma_f32_32x32x16_bf16(a11, b11, acc11, 0, 0, 0); \
        __builtin_amdgcn_s_setprio(0);                                        \
        asm volatile("s_waitcnt lgkmcnt(0)" ::: "memory");                    \
        __builtin_amdgcn_s_barrier();                                         \
        __builtin_amdgcn_sched_barrier(0);                                    \
    } while (0)

    // prologue: tile 0 -> set 0 (outstanding = 4, matches steady state)
    STAGE_ALL(0, 0);

    for (int t = 0; t < NT; t += 2) {
        const int tn1 = t + 1;                          // <= NT-1
        KTILE(0, tn1);
        const int tn2 = (t + 2 < NT) ? t + 2 : NT - 1;  // tail: redundant restage
        KTILE(1, tn2);
    }

    // ---- epilogue: 32x32 C/D layout (m74/m101; validated in R10):
    // col = lane&31, row = (reg&3) + 8*(reg>>2) + 4*hi
    {
        const int crowB = bm * 128 + wr * 64 + 4 * hi;
        const int ccolB = bn * 128 + wc * 64 + lo;
#pragma unroll
        for (int reg = 0; reg < 16; ++reg) {
            const int row = crowB + (reg & 3) + 8 * (reg >> 2);
            C[(size_t)row * N + ccolB]            = acc00[reg];
            C[(size_t)row * N + ccolB + 32]       = acc01[reg];
            C[(size_t)(row + 32) * N + ccolB]     = acc10[reg];
            C[(size_t)(row + 32) * N + ccolB + 32]= acc11[reg];
        }
    }

#undef STAGE_ALL
#undef KTILE
}

// ---------------- fallback: Round-4 fused kernel (proven PASS) ----------------
__device__ inline int lds_off(int row, int slot) {
    return row * 32 + (((slot ^ ((row >> 1) & 3)) & 3) << 3);
}

__global__ __launch_bounds__(256) void gemm_bt_fused(
    const float* __restrict__ A, const float* __restrict__ B,
    float* __restrict__ C, int M, int N, int K)
{
    constexpr int BM = 128, BN = 128, BK = 32;
    __shared__ unsigned short sA[2][BM * BK];
    __shared__ unsigned short sB[2][BN * BK];

    const int nbm = M / BM, nbn = N / BN;
    const int nwg = nbm * nbn;
    const int bid = blockIdx.x;
    int swz = bid;
    if ((nwg & 7) == 0) { const int q = nwg >> 3; swz = (bid & 7) * q + (bid >> 3); }
    const int bm = swz % nbm, bn = swz / nbm;

    const int tid = threadIdx.x;
    const int srow = tid >> 1;
    const int scol = (tid & 1) * 16;
    const float* gA = A + (size_t)(bm * BM + srow) * K + scol;
    const float* gB = B + (size_t)(bn * BN + srow) * K + scol;
    const int s0  = (tid & 1) * 2;
    const int wo0 = lds_off(srow, s0);
    const int wo1 = lds_off(srow, s0 + 1);

    const int wave = tid >> 6, lane = tid & 63;
    const int wr = wave >> 1, wc = wave & 1;
    const int fr = lane & 15;
    const int slr = lane >> 4;
    int offA[4], offB[4];
#pragma unroll
    for (int i = 0; i < 4; ++i) {
        offA[i] = lds_off(wr * 64 + i * 16 + fr, slr);
        offB[i] = lds_off(wc * 64 + i * 16 + fr, slr);
    }

    f32x4 acc[4][4] = {};
    const int NT = K / BK;

    float4 va[4], vb[4];
#pragma unroll
    for (int p = 0; p < 4; ++p) {
        va[p] = *reinterpret_cast<const float4*>(gA + p * 4);
        vb[p] = *reinterpret_cast<const float4*>(gB + p * 4);
    }

    for (int t = 0; t < NT; ++t) {
        const int cur = t & 1;
        u16x8 pa0, pa1, pb0, pb1;
#pragma unroll
        for (int e = 0; e < 4; ++e) {
            pa0[e] = f2bf(va[0][e]);  pa0[4 + e] = f2bf(va[1][e]);
            pa1[e] = f2bf(va[2][e]);  pa1[4 + e] = f2bf(va[3][e]);
            pb0[e] = f2bf(vb[0][e]);  pb0[4 + e] = f2bf(vb[1][e]);
            pb1[e] = f2bf(vb[2][e]);  pb1[4 + e] = f2bf(vb[3][e]);
        }
        *reinterpret_cast<u16x8*>(&sA[cur][wo0]) = pa0;
        *reinterpret_cast<u16x8*>(&sA[cur][wo1]) = pa1;
        *reinterpret_cast<u16x8*>(&sB[cur][wo0]) = pb0;
        *reinterpret_cast<u16x8*>(&sB[cur][wo1]) = pb1;

        const int kn = (t + 1 < NT) ? (t + 1) * BK : t * BK;
#pragma unroll
        for (int p = 0; p < 4; ++p) {
            va[p] = *reinterpret_cast<const float4*>(gA + kn + p * 4);
            vb[p] = *reinterpret_cast<const float4*>(gB + kn + p * 4);
        }

        __syncthreads();

        bf16x8 a[4], b[4];
#pragma unroll
        for (int i = 0; i < 4; ++i) a[i] = *reinterpret_cast<const bf16x8*>(&sA[cur][offA[i]]);
#pragma unroll
        for (int j = 0; j < 4; ++j) b[j] = *reinterpret_cast<const bf16x8*>(&sB[cur][offB[j]]);
#pragma unroll
        for (int i = 0; i < 4; ++i)
#pragma unroll
            for (int j = 0; j < 4; ++j)
                acc[i][j] = __builtin_amdgcn_mfma_f32_16x16x32_bf16(a[i], b[j], acc[i][j], 0, 0, 0);
    }

    const int crow0 = bm * BM + wr * 64 + (lane >> 4) * 4;
    const int ccol0 = bn * BN + wc * 64 + fr;
#pragma unroll
    for (int i = 0; i < 4; ++i)
#pragma unroll
        for (int j = 0; j < 4; ++j)
#pragma unroll
            for (int r = 0; r < 4; ++r)
                C[(size_t)(crow0 + i * 16 + r) * N + (ccol0 + j * 16)] = acc[i][j][r];
}

extern "C" void kernel_launch(void* const* d_in, const int* in_sizes, int n_in,
                              void* d_out, int out_size, void* d_ws, size_t ws_size,
                              hipStream_t stream) {
    int K = 4096;
    int M = in_sizes[0] / K;   // 2048
    int N = in_sizes[1] / K;   // 8192

    const float* x = (const float*)d_in[0];
    const float* w = (const float*)d_in[1];
    float* out     = (float*)d_out;
    unsigned short* wsp = (unsigned short*)d_ws;

    const size_t need = ((size_t)in_sizes[0] + (size_t)in_sizes[1]) * 2;
    const int nwg2 = (M >> 7) * (N >> 7);   // 1024

    bool geom_ok = (M % 128 == 0) && (N % 128 == 0) && (K % 64 == 0) &&
                   ((nwg2 & 7) == 0);
    int maxB = 0;
    hipError_t oe = hipOccupancyMaxActiveBlocksPerMultiprocessor(&maxB, coop_cvt_gemm6, 256, 0);
    const bool coop_ok = geom_ok && (oe == hipSuccess) && (ws_size >= need) &&
                         ((long long)maxB * 256 >= (long long)nwg2);

    if (coop_ok) {
        void* args[] = {(void*)&x, (void*)&w, (void*)&wsp, (void*)&out,
                        (void*)&M, (void*)&N, (void*)&K};
        hipError_t le = hipLaunchCooperativeKernel(coop_cvt_gemm6, dim3(nwg2), dim3(256),
                                                   args, 0, stream);
        if (le == hipSuccess) return;
    }
    const int nwg = (M / 128) * (N / 128);
    gemm_bt_fused<<<dim3(nwg), dim3(256), 0, stream>>>(x, w, out, M, N, K);
}